// Round 1
// baseline (524.073 us; speedup 1.0000x reference)
//
#include <hip/hip_runtime.h>

constexpr int kN = 131072;
constexpr int kC = 128;

__device__ __forceinline__ unsigned fmap(float f) {
    unsigned b = __float_as_uint(f);
    return (b & 0x80000000u) ? ~b : (b | 0x80000000u);
}

__global__ __launch_bounds__(256, 4) void margins_kernel(
    const float* __restrict__ p0, const float* __restrict__ p1,
    const float* __restrict__ p2, const float* __restrict__ p3,
    const float* __restrict__ p4, const float* __restrict__ p5,
    const float* __restrict__ p6, const float* __restrict__ p7,
    const int* __restrict__ targets, float* __restrict__ out,
    unsigned* __restrict__ gmax_ws)
{
    const int tid  = threadIdx.x;
    const int wave = tid >> 6;
    const int lane = tid & 63;
    const int sub  = lane & 31;   // lane within 32-lane row group
    const int half = lane >> 5;   // which of the wave's 2 rows
    const int row  = blockIdx.x * 8 + wave * 2 + half;

    const float* preds[8] = {p0, p1, p2, p3, p4, p5, p6, p7};

    const int tgt   = targets[row];
    const int tlane = (lane & 32) | (tgt >> 2);  // lane holding the target col (same half)
    const int tsub  = tgt & 3;

    const size_t rowoff = (size_t)row * kC + sub * 4;

    float margins[8];
    float gmax = -3.4e38f;

#pragma unroll
    for (int j = 0; j < 8; ++j) {
        const float4 v = *(const float4*)(preds[j] + rowoff);
        // local top-2 of 4 elements
        float a1 = fmaxf(v.x, v.y), a2 = fminf(v.x, v.y);
        float b1 = fmaxf(v.z, v.w), b2 = fminf(v.z, v.w);
        float m1 = fmaxf(a1, b1);
        float m2 = fmaxf(fminf(a1, b1), fmaxf(a2, b2));
        float tv = (tsub == 0) ? v.x : (tsub == 1) ? v.y : (tsub == 2) ? v.z : v.w;
        // butterfly top-2 reduction across the 32-lane group (masks 1..16 stay in-half)
#pragma unroll
        for (int off = 1; off < 32; off <<= 1) {
            float om1 = __shfl_xor(m1, off, 64);
            float om2 = __shfl_xor(m2, off, 64);
            float lo  = fminf(m1, om1);
            m1 = fmaxf(m1, om1);
            m2 = fmaxf(fmaxf(m2, om2), lo);
        }
        tv = __shfl(tv, tlane, 64);
        margins[j] = (tv == m1) ? (m1 - m2) : 0.0f;
        if (j < 7) gmax = fmaxf(gmax, m1);
    }

    // softmax over margins / T (T = 2); margins uniform within each 32-lane group
    float mmax = margins[0];
#pragma unroll
    for (int j = 1; j < 8; ++j) mmax = fmaxf(mmax, margins[j]);
    float e[8];
    float s = 0.0f;
#pragma unroll
    for (int j = 0; j < 8; ++j) { e[j] = __expf((margins[j] - mmax) * 0.5f); s += e[j]; }
    const float inv = 1.0f / s;

    if (sub < 2) {
        float4 w;
        if (sub == 0) w = make_float4(e[0] * inv, e[1] * inv, e[2] * inv, e[3] * inv);
        else          w = make_float4(e[4] * inv, e[5] * inv, e[6] * inv, e[7] * inv);
        *(float4*)(out + 1 + (size_t)row * 8 + sub * 4) = w;
    }

    // global max over predictors 0..6
    gmax = fmaxf(gmax, __shfl_xor(gmax, 32, 64));
    __shared__ float smax[4];
    if (lane == 0) smax[wave] = gmax;
    __syncthreads();
    if (tid == 0) {
        float b = fmaxf(fmaxf(smax[0], smax[1]), fmaxf(smax[2], smax[3]));
        atomicMax(gmax_ws, fmap(b));
    }
}

__global__ void finalize_kernel(const unsigned* __restrict__ gmax_ws,
                                float* __restrict__ out)
{
    unsigned u = *gmax_ws;
    unsigned b = (u & 0x80000000u) ? (u & 0x7FFFFFFFu) : ~u;
    out[0] = __uint_as_float(b);
}

extern "C" void kernel_launch(void* const* d_in, const int* in_sizes, int n_in,
                              void* d_out, int out_size, void* d_ws, size_t ws_size,
                              hipStream_t stream) {
    const float* p0 = (const float*)d_in[0];
    const float* p1 = (const float*)d_in[1];
    const float* p2 = (const float*)d_in[2];
    const float* p3 = (const float*)d_in[3];
    const float* p4 = (const float*)d_in[4];
    const float* p5 = (const float*)d_in[5];
    const float* p6 = (const float*)d_in[6];
    const float* p7 = (const float*)d_in[7];
    const int* targets = (const int*)d_in[8];
    float* out = (float*)d_out;
    unsigned* ws = (unsigned*)d_ws;

    hipMemsetAsync(ws, 0, sizeof(unsigned), stream);

    dim3 grid(kN / 8), block(256);
    margins_kernel<<<grid, block, 0, stream>>>(p0, p1, p2, p3, p4, p5, p6, p7,
                                               targets, out, ws);
    finalize_kernel<<<1, 1, 0, stream>>>(ws, out);
}

// Round 2
// 460.334 us; speedup vs baseline: 1.1385x; 1.1385x over previous
//
#include <hip/hip_runtime.h>
#include <cfloat>

constexpr int kN = 131072;
constexpr int kC = 128;
constexpr int kRows = 16;   // rows per block

__device__ __forceinline__ unsigned fmap(float f) {
    unsigned b = __float_as_uint(f);
    return (b & 0x80000000u) ? ~b : (b | 0x80000000u);
}

__global__ __launch_bounds__(256, 4) void margins_kernel(
    const float* __restrict__ p0, const float* __restrict__ p1,
    const float* __restrict__ p2, const float* __restrict__ p3,
    const float* __restrict__ p4, const float* __restrict__ p5,
    const float* __restrict__ p6, const float* __restrict__ p7,
    const int* __restrict__ targets, float* __restrict__ out,
    unsigned* __restrict__ gmax_ws)
{
    // pitch 34 float2 per row: 272 B row stride (16B aligned), breaks pow2 banks
    __shared__ float2 P2[8][kRows][34];   // [pred][row][chunk] (m1,m2) partials
    __shared__ float tvbuf[8][17];        // target value per (pred,row)
    __shared__ float marg[kRows][12];     // margins, pitch 12 (48 B, 16B aligned)
    __shared__ unsigned blockmax;

    const int t = threadIdx.x;
    const int row0 = blockIdx.x * kRows;
    if (t == 0) blockmax = 0u;

    const float* preds[8] = {p0, p1, p2, p3, p4, p5, p6, p7};

    // ---- stage 1: load 16 rows x 128 cols x 8 preds, in-lane top2-of-4 ----
    const int c  = t & 31;        // chunk (float4 index within row)
    const int a0 = t >> 5;        // 0..7

#pragma unroll
    for (int it = 0; it < 2; ++it) {
        const int a   = a0 + it * 8;          // row within tile, 0..15
        const int row = row0 + a;
        const int tgt = targets[row];
        const size_t off = (size_t)row * kC + c * 4;

        float4 v[8];
#pragma unroll
        for (int j = 0; j < 8; ++j) v[j] = *(const float4*)(preds[j] + off);

        const bool hasT = (tgt >> 2) == c;
        const int  ts   = tgt & 3;

#pragma unroll
        for (int j = 0; j < 8; ++j) {
            const float4 w = v[j];
            float a1 = fmaxf(w.x, w.y), a2 = fminf(w.x, w.y);
            float b1 = fmaxf(w.z, w.w), b2 = fminf(w.z, w.w);
            float m1 = fmaxf(a1, b1);
            float m2 = fmaxf(fminf(a1, b1), fmaxf(a2, b2));
            P2[j][a][c] = make_float2(m1, m2);
            if (hasT) {
                float tv = (ts == 0) ? w.x : (ts == 1) ? w.y : (ts == 2) ? w.z : w.w;
                tvbuf[j][a] = tv;
            }
        }
    }
    __syncthreads();

    // ---- stage 2: one thread per (row,pred) folds 32 (m1,m2) pairs ----
    if (t < 128) {
        const int r = t & 15;
        const int j = t >> 4;
        const float4* pr = (const float4*)(&P2[j][r][0]);
        float m1 = -FLT_MAX, m2 = -FLT_MAX;
#pragma unroll
        for (int k = 0; k < 16; ++k) {   // 16 x float4 = 32 pairs
            const float4 q = pr[k];
            float lo = fminf(m1, q.x);
            m1 = fmaxf(m1, q.x);
            m2 = fmaxf(fmaxf(m2, q.y), lo);
            lo = fminf(m1, q.z);
            m1 = fmaxf(m1, q.z);
            m2 = fmaxf(fmaxf(m2, q.w), lo);
        }
        const float tv = tvbuf[j][r];
        marg[r][j] = (tv == m1) ? (m1 - m2) : 0.0f;
        if (j < 7) atomicMax(&blockmax, fmap(m1));  // preds 0..6 only
    }
    __syncthreads();

    // ---- stage 3: softmax over 8 margins per row; coalesced scalar stores ----
    if (t < 128) {
        const int r  = t >> 3;
        const int jj = t & 7;
        const float4 ma = *(const float4*)&marg[r][0];
        const float4 mb = *(const float4*)&marg[r][4];
        float mm = fmaxf(fmaxf(fmaxf(ma.x, ma.y), fmaxf(ma.z, ma.w)),
                         fmaxf(fmaxf(mb.x, mb.y), fmaxf(mb.z, mb.w)));
        const float e0 = __expf((ma.x - mm) * 0.5f);
        const float e1 = __expf((ma.y - mm) * 0.5f);
        const float e2 = __expf((ma.z - mm) * 0.5f);
        const float e3 = __expf((ma.w - mm) * 0.5f);
        const float e4 = __expf((mb.x - mm) * 0.5f);
        const float e5 = __expf((mb.y - mm) * 0.5f);
        const float e6 = __expf((mb.z - mm) * 0.5f);
        const float e7 = __expf((mb.w - mm) * 0.5f);
        const float s  = e0 + e1 + e2 + e3 + e4 + e5 + e6 + e7;
        float num = (jj == 0) ? e0 : (jj == 1) ? e1 : (jj == 2) ? e2 :
                    (jj == 3) ? e3 : (jj == 4) ? e4 : (jj == 5) ? e5 :
                    (jj == 6) ? e6 : e7;
        out[1 + (size_t)row0 * 8 + t] = num / s;
    }
    if (t == 0) atomicMax(gmax_ws, blockmax);
}

__global__ void finalize_kernel(const unsigned* __restrict__ gmax_ws,
                                float* __restrict__ out)
{
    unsigned u = *gmax_ws;
    unsigned b = (u & 0x80000000u) ? (u & 0x7FFFFFFFu) : ~u;
    out[0] = __uint_as_float(b);
}

extern "C" void kernel_launch(void* const* d_in, const int* in_sizes, int n_in,
                              void* d_out, int out_size, void* d_ws, size_t ws_size,
                              hipStream_t stream) {
    const float* p0 = (const float*)d_in[0];
    const float* p1 = (const float*)d_in[1];
    const float* p2 = (const float*)d_in[2];
    const float* p3 = (const float*)d_in[3];
    const float* p4 = (const float*)d_in[4];
    const float* p5 = (const float*)d_in[5];
    const float* p6 = (const float*)d_in[6];
    const float* p7 = (const float*)d_in[7];
    const int* targets = (const int*)d_in[8];
    float* out = (float*)d_out;
    unsigned* ws = (unsigned*)d_ws;

    hipMemsetAsync(ws, 0, sizeof(unsigned), stream);

    dim3 grid(kN / kRows), block(256);
    margins_kernel<<<grid, block, 0, stream>>>(p0, p1, p2, p3, p4, p5, p6, p7,
                                               targets, out, ws);
    finalize_kernel<<<1, 1, 0, stream>>>(ws, out);
}